// Round 20
// baseline (46.158 us; speedup 1.0000x reference)
//
#include <hip/hip_runtime.h>

// OurButterflyLayer: N=4096, LOGN=12, IN=1024, OUT=4096, BATCH=8192
//
// out[s,j] = scale[j] * z_s[src[j]],  z_s = 10-stage butterfly (stages 0..9)
// on the 1024-float input row s; stages 10,11 + out-row gather fold into
// per-output (scale, src) pairs (elements >=1024 stay zero through stages
// 0..9 since all strides < 1024).
//
// Round-20: 4 samples/wave with real VGPR headroom. Insight: a 512-thr block
// needs 8 co-resident waves = 2/SIMD -> hard 128-VGPR cap (why R14/R16/R17
// spilled). 256-thr blocks (4 waves = 1/SIMD) allow 256 VGPR. Structure:
// 512 blocks x 256 thr, x[4][16], all 20 coeff rows in 80 KB swizzled LDS
// (R13-verified), 4 x 16 KB f4-slot z scratch (R8-verified algebra: one
// ds_read_b128 + one src/scale pair serves FOUR samples). Exchanges =
// R19-verified (DPP d=1,2,8 | shfl d=4 | permlane builtin d=16,32).
// Plain loads/stores, one barrier, pipelined epilogue.

typedef float f4 __attribute__((ext_vector_type(4)));
typedef int   i4 __attribute__((ext_vector_type(4)));

__device__ __forceinline__ int swz(int e) {
    // XOR float-index bits [6:5] into [3:2]: keeps float4 alignment; makes
    // 64B-stride LDS coeff accesses bank-conflict-free.
    return e ^ (((e >> 5) & 3) << 2);
}

template<int CTRL>
__device__ __forceinline__ float dppx(float x) {
    int xi = __builtin_bit_cast(int, x);
    int r  = __builtin_amdgcn_update_dpp(xi, xi, CTRL, 0xF, 0xF, true);
    return __builtin_bit_cast(float, r);
}
// ctrl: quad_perm(1,0,3,2)=0xB1 (lane^1), quad_perm(2,3,0,1)=0x4E (lane^2),
// row_ror:8=0x128 (lane^8 within 16-lane row). Verified R4/R6/R7/R10/R13/R19.

#if __has_builtin(__builtin_amdgcn_permlane16_swap) && __has_builtin(__builtin_amdgcn_permlane32_swap)
// lane^16 / lane^32 partner via permlane swap builtin (compiler handles the
// DPP-class read-after-write hazards). XOR-combine is exact and
// direction-proof. Verified R19.
__device__ __forceinline__ float xswap16(float x) {
    unsigned xi = __builtin_bit_cast(unsigned, x);
    auto r = __builtin_amdgcn_permlane16_swap(xi, xi, false, false);
    return __builtin_bit_cast(float, r[0] ^ r[1] ^ xi);
}
__device__ __forceinline__ float xswap32(float x) {
    unsigned xi = __builtin_bit_cast(unsigned, x);
    auto r = __builtin_amdgcn_permlane32_swap(xi, xi, false, false);
    return __builtin_bit_cast(float, r[0] ^ r[1] ^ xi);
}
#else
__device__ __forceinline__ float xswap16(float x) { return __shfl_xor(x, 16, 64); }
__device__ __forceinline__ float xswap32(float x) { return __shfl_xor(x, 32, 64); }
#endif

__global__ void __launch_bounds__(256) bfly_prep(
    const float* __restrict__ lp, const int* __restrict__ orow,
    float* __restrict__ scale, int* __restrict__ src4)
{
    int j = blockIdx.x * 256 + threadIdx.x;
    if (j >= 4096) return;
    int r = orow[j];
    int c = r & 1023;
    int u = r & 2047;
    const float* A10 = lp + 20 * 4096;
    const float* B10 = lp + 21 * 4096;
    const float* A11 = lp + 22 * 4096;
    const float* B11 = lp + 23 * 4096;
    float f11 = (r & 2048) ? B11[u] : A11[u];
    float f10 = (r & 1024) ? B10[c] : A10[c];
    scale[j] = f11 * f10;
    // f4-slot index with bank-spreading bijection (XOR bits [6:4] into
    // [2:0]); matches the write-side (lane*16+k)^(lane&7). Verified R8.
    src4[j] = c ^ ((c >> 4) & 7);
}

__global__ void __launch_bounds__(256, 1) bfly_main(
    const float* __restrict__ inp, const float* __restrict__ lp,
    const float* __restrict__ scale, const int* __restrict__ src4,
    float* __restrict__ out)
{
    // [0, 20480): 20 coeff rows (stages 0..9 a,b), swizzled. persistent.
    // [20480, 36864): 4 waves x 1024 f4 z-slots (16 KB each). Total 144 KB.
    __shared__ __align__(16) float cf[20 * 1024 + 4 * 4096];
    const int t = threadIdx.x;
    const int wave = t >> 6, lane = t & 63;

    // cooperative coeff staging: rows 0..19 of lp (first 1024 floats each);
    // 256 threads stage one row per step.
    #pragma unroll
    for (int q = 0; q < 20; ++q) {
        const int e = t * 4;
        const f4 v = *reinterpret_cast<const f4*>(lp + (size_t)q * 4096 + e);
        *reinterpret_cast<f4*>(&cf[q * 1024 + swz(e)]) = v;
    }

    const int sBase = blockIdx.x * 16 + wave * 4;   // 4 samples per wave
    float x[4][16];
    #pragma unroll
    for (int m = 0; m < 4; ++m) {
        const f4* p = reinterpret_cast<const f4*>(inp + (size_t)(sBase + m) * 1024 + lane * 16);
        #pragma unroll
        for (int c = 0; c < 4; ++c) {
            f4 v = p[c];
            x[m][4*c+0] = v.x; x[m][4*c+1] = v.y; x[m][4*c+2] = v.z; x[m][4*c+3] = v.w;
        }
    }

    __syncthreads();   // cf ready — the only barrier in the kernel

    // ---- stages 0,1 (s=1,2): pairs within each f4 quarter; coeff from LDS ----
    #pragma unroll
    for (int i = 0; i < 2; ++i) {
        const float* arow = &cf[(size_t)(2*i)     * 1024];
        const float* brow = &cf[(size_t)(2*i + 1) * 1024];
        #pragma unroll
        for (int c = 0; c < 4; ++c) {
            f4 va = *reinterpret_cast<const f4*>(&arow[swz(lane * 16 + 4 * c)]);
            f4 vb = *reinterpret_cast<const f4*>(&brow[swz(lane * 16 + 4 * c)]);
            #pragma unroll
            for (int m = 0; m < 4; ++m) {
                float* xm = x[m];
                if (i == 0) {          // pairs (0,1),(2,3)
                    float lo0 = xm[4*c+0], hi0 = xm[4*c+1];
                    xm[4*c+0] = va[0] * lo0 + vb[1] * hi0;
                    xm[4*c+1] = va[1] * hi0 + vb[0] * lo0;
                    float lo1 = xm[4*c+2], hi1 = xm[4*c+3];
                    xm[4*c+2] = va[2] * lo1 + vb[3] * hi1;
                    xm[4*c+3] = va[3] * hi1 + vb[2] * lo1;
                } else {               // pairs (0,2),(1,3)
                    float lo0 = xm[4*c+0], hi0 = xm[4*c+2];
                    xm[4*c+0] = va[0] * lo0 + vb[2] * hi0;
                    xm[4*c+2] = va[2] * hi0 + vb[0] * lo0;
                    float lo1 = xm[4*c+1], hi1 = xm[4*c+3];
                    xm[4*c+1] = va[1] * lo1 + vb[3] * hi1;
                    xm[4*c+3] = va[3] * hi1 + vb[1] * lo1;
                }
            }
        }
    }

    // ---- stages 2,3 (s=4,8): pairs across quarters; coeff from LDS ----
    #pragma unroll
    for (int i = 2; i < 4; ++i) {
        const float* arow = &cf[(size_t)(2*i)     * 1024];
        const float* brow = &cf[(size_t)(2*i + 1) * 1024];
        #pragma unroll
        for (int g = 0; g < 2; ++g) {
            const int q0 = (i == 2) ? 2 * g : g;       // s=4: (0,1),(2,3)
            const int q1 = (i == 2) ? q0 + 1 : q0 + 2; // s=8: (0,2),(1,3)
            f4 va0 = *reinterpret_cast<const f4*>(&arow[swz(lane * 16 + 4 * q0)]);
            f4 va1 = *reinterpret_cast<const f4*>(&arow[swz(lane * 16 + 4 * q1)]);
            f4 vb0 = *reinterpret_cast<const f4*>(&brow[swz(lane * 16 + 4 * q0)]);
            f4 vb1 = *reinterpret_cast<const f4*>(&brow[swz(lane * 16 + 4 * q1)]);
            #pragma unroll
            for (int m = 0; m < 4; ++m) {
                float* xm = x[m];
                #pragma unroll
                for (int e = 0; e < 4; ++e) {
                    float lo = xm[4*q0+e], hi = xm[4*q1+e];
                    xm[4*q0+e] = va0[e] * lo + vb1[e] * hi;
                    xm[4*q1+e] = va1[e] * hi + vb0[e] * lo;
                }
            }
        }
    }

    // ---- stage 4 (d=1): DPP quad_perm exchange; coeff rows 8,9 from LDS ----
    {
        const float* arow = &cf[(size_t)8 * 1024];
        const float* brow = &cf[(size_t)9 * 1024];
        #pragma unroll
        for (int c = 0; c < 4; ++c) {
            f4 va = *reinterpret_cast<const f4*>(&arow[swz(lane * 16 + 4 * c)]);
            f4 vb = *reinterpret_cast<const f4*>(&brow[swz((lane ^ 1) * 16 + 4 * c)]);
            #pragma unroll
            for (int m = 0; m < 4; ++m) {
                #pragma unroll
                for (int e = 0; e < 4; ++e) {
                    float v = x[m][4*c+e];
                    x[m][4*c+e] = va[e] * v + vb[e] * dppx<0xB1>(v);
                }
            }
        }
    }

    // ---- stages 5..9 (d=2,4,8,16,32): coeff rows 10..19 from LDS ----
    // exchange pipes: d=2,8 DPP | d=4 shfl (DS) | d=16,32 permlane builtin
    #pragma unroll
    for (int i = 5; i < 10; ++i) {
        const int d = 1 << (i - 4);
        const float* arow = &cf[(size_t)(2*i)     * 1024];
        const float* brow = &cf[(size_t)(2*i + 1) * 1024];
        #pragma unroll
        for (int c = 0; c < 4; ++c) {
            f4 va = *reinterpret_cast<const f4*>(&arow[swz(lane * 16 + 4 * c)]);
            f4 vb = *reinterpret_cast<const f4*>(&brow[swz((lane ^ d) * 16 + 4 * c)]);
            #pragma unroll
            for (int m = 0; m < 4; ++m) {
                #pragma unroll
                for (int e = 0; e < 4; ++e) {
                    float v = x[m][4*c+e];
                    float xp = (d == 2)  ? dppx<0x4E>(v)
                             : (d == 8)  ? dppx<0x128>(v)
                             : (d == 16) ? xswap16(v)
                             : (d == 32) ? xswap32(v)
                             :             __shfl_xor(v, d, 64);   // d = 4
                    x[m][4*c+e] = va[e] * v + vb[e] * xp;
                }
            }
        }
    }

    // z write (R8-verified slot algebra): f4-slot (lane*16+k)^(lane&7)
    // holds {z0,z1,z2,z3}[element].
    f4* zz = reinterpret_cast<f4*>(&cf[20 * 1024]) + (size_t)wave * 1024;
    const int km = lane & 7;
    #pragma unroll
    for (int k = 0; k < 16; ++k) {
        f4 v = { x[0][k], x[1][k], x[2][k], x[3][k] };
        zz[(lane * 16 + k) ^ km] = v;
    }

    // epilogue (R8-verified): one b128 LDS read + one src/scale pair serves
    // 4 samples; loads pipelined 1 deep ahead of the stores. Wave-private
    // region, no barrier needed.
    const i4* srv = reinterpret_cast<const i4*>(src4);
    const f4* scv = reinterpret_cast<const f4*>(scale);
    f4* o0 = reinterpret_cast<f4*>(out + (size_t)(sBase + 0) * 4096);
    f4* o1 = reinterpret_cast<f4*>(out + (size_t)(sBase + 1) * 4096);
    f4* o2 = reinterpret_cast<f4*>(out + (size_t)(sBase + 2) * 4096);
    f4* o3 = reinterpret_cast<f4*>(out + (size_t)(sBase + 3) * 4096);

    i4 si = srv[lane];
    f4 sc = scv[lane];
    #pragma unroll
    for (int it = 0; it < 16; ++it) {
        i4 si_c = si;
        f4 sc_c = sc;
        if (it + 1 < 16) {                      // prefetch next iteration
            si = srv[(it + 1) * 64 + lane];
            sc = scv[(it + 1) * 64 + lane];
        }
        int j4 = it * 64 + lane;
        f4 vx = zz[si_c.x];
        f4 vy = zz[si_c.y];
        f4 vz = zz[si_c.z];
        f4 vw = zz[si_c.w];
        f4 r0 = { sc_c.x * vx[0], sc_c.y * vy[0], sc_c.z * vz[0], sc_c.w * vw[0] };
        f4 r1 = { sc_c.x * vx[1], sc_c.y * vy[1], sc_c.z * vz[1], sc_c.w * vw[1] };
        f4 r2 = { sc_c.x * vx[2], sc_c.y * vy[2], sc_c.z * vz[2], sc_c.w * vw[2] };
        f4 r3 = { sc_c.x * vx[3], sc_c.y * vy[3], sc_c.z * vz[3], sc_c.w * vw[3] };
        o0[j4] = r0;
        o1[j4] = r1;
        o2[j4] = r2;
        o3[j4] = r3;
    }
}

extern "C" void kernel_launch(void* const* d_in, const int* in_sizes, int n_in,
                              void* d_out, int out_size, void* d_ws, size_t ws_size,
                              hipStream_t stream) {
    const float* inp  = (const float*)d_in[0];   // (8192, 1024) f32
    const float* lp   = (const float*)d_in[1];   // (24, 4096)  f32
    const int*   orow = (const int*)d_in[2];     // (4096,)     i32
    float* out = (float*)d_out;                  // (8192, 4096) f32

    float* scale = (float*)d_ws;                       // 4096 f32
    int*   src4  = (int*)((char*)d_ws + 4096 * 4);     // 4096 i32 (f4-slot idx)

    bfly_prep<<<16, 256, 0, stream>>>(lp, orow, scale, src4);
    bfly_main<<<512, 256, 0, stream>>>(inp, lp, scale, src4, out);
}

// Round 21
// 43.759 us; speedup vs baseline: 1.0548x; 1.0548x over previous
//
#include <hip/hip_runtime.h>

// OurButterflyLayer: N=4096, LOGN=12, IN=1024, OUT=4096, BATCH=8192
//
// out[s,j] = scale[j] * z_s[src[j]],  z_s = 10-stage butterfly (stages 0..9)
// on the 1024-float input row s; stages 10,11 + out-row gather fold into
// per-output (scale, src) pairs (elements >=1024 stay zero through stages
// 0..9 since all strides < 1024).
//
// Round-21: R19 (best, 41.8 us) with the z scratch OVERLAID onto the coeff
// LDS (rows 0..15 are dead after the last coeff read). LDS/block 144->80 KB
// -> 2 concurrent blocks/CU = 16 waves/CU (vs 8): the two blocks' compute /
// store phases interleave on the SIMDs instead of the whole CU phase-
// marching, and there is no sequential block handoff. Cost: one extra
// __syncthreads before zwrite. All math/layout/exchange code is R19
// byte-identical (DPP d=1,2,8 | shfl d=4 | permlane builtin d=16,32;
// pair-swizzled f2 z slots; pipelined paired epilogue; plain loads/stores).

typedef float f4 __attribute__((ext_vector_type(4)));
typedef float f2 __attribute__((ext_vector_type(2)));
typedef int   i4 __attribute__((ext_vector_type(4)));

__device__ __forceinline__ int swz(int e) {
    // XOR float-index bits [6:5] into [3:2]: keeps float4 alignment; makes
    // 64B-stride LDS coeff accesses bank-conflict-free.
    return e ^ (((e >> 5) & 3) << 2);
}

template<int CTRL>
__device__ __forceinline__ float dppx(float x) {
    int xi = __builtin_bit_cast(int, x);
    int r  = __builtin_amdgcn_update_dpp(xi, xi, CTRL, 0xF, 0xF, true);
    return __builtin_bit_cast(float, r);
}
// ctrl: quad_perm(1,0,3,2)=0xB1 (lane^1), quad_perm(2,3,0,1)=0x4E (lane^2),
// row_ror:8=0x128 (lane^8 within 16-lane row). Verified R4/R6/R7/R10/R13/R19.

#if __has_builtin(__builtin_amdgcn_permlane16_swap) && __has_builtin(__builtin_amdgcn_permlane32_swap)
// lane^16 / lane^32 partner via permlane swap builtin (compiler handles the
// DPP-class read-after-write hazards). XOR-combine is exact and
// direction-proof. Verified R19.
__device__ __forceinline__ float xswap16(float x) {
    unsigned xi = __builtin_bit_cast(unsigned, x);
    auto r = __builtin_amdgcn_permlane16_swap(xi, xi, false, false);
    return __builtin_bit_cast(float, r[0] ^ r[1] ^ xi);
}
__device__ __forceinline__ float xswap32(float x) {
    unsigned xi = __builtin_bit_cast(unsigned, x);
    auto r = __builtin_amdgcn_permlane32_swap(xi, xi, false, false);
    return __builtin_bit_cast(float, r[0] ^ r[1] ^ xi);
}
#else
__device__ __forceinline__ float xswap16(float x) { return __shfl_xor(x, 16, 64); }
__device__ __forceinline__ float xswap32(float x) { return __shfl_xor(x, 32, 64); }
#endif

__global__ void __launch_bounds__(256) bfly_prep(
    const float* __restrict__ lp, const int* __restrict__ orow,
    float* __restrict__ scale, int* __restrict__ src2)
{
    int j = blockIdx.x * 256 + threadIdx.x;
    if (j >= 4096) return;
    int r = orow[j];
    int c = r & 1023;
    int u = r & 2047;
    const float* A10 = lp + 20 * 4096;
    const float* B10 = lp + 21 * 4096;
    const float* A11 = lp + 22 * 4096;
    const float* B11 = lp + 23 * 4096;
    float f11 = (r & 2048) ? B11[u] : A11[u];
    float f10 = (r & 1024) ? B10[c] : A10[c];
    scale[j] = f11 * f10;
    // f2-slot index with pair-preserving bank spread:
    // pz(c) = c ^ (((c>>4)&7)<<1)   (matches z-write slot algebra below)
    src2[j] = c ^ (((c >> 4) & 7) << 1);
}

__global__ void __launch_bounds__(512, 2) bfly_main(
    const float* __restrict__ inp, const float* __restrict__ lp,
    const float* __restrict__ scale, const int* __restrict__ src2,
    float* __restrict__ out)
{
    // 20 coeff rows (stages 0..9 a,b), swizzled. After the 2nd barrier the
    // first 16 KB-rows are dead and rows 0..15 are overlaid with the 8
    // per-wave paired-f2 z regions (8 KB each). 80 KB total -> 2 blocks/CU.
    __shared__ __align__(16) float cf[20 * 1024];
    const int t = threadIdx.x;
    const int wave = t >> 6, lane = t & 63;

    // cooperative coeff staging: rows 0..19 of lp (first 1024 floats each);
    // 512 threads stage two rows per step.
    #pragma unroll
    for (int step = 0; step < 10; ++step) {
        const int q = 2 * step + (t >> 8);
        const int e = (t & 255) * 4;
        const f4 v = *reinterpret_cast<const f4*>(lp + (size_t)q * 4096 + e);
        *reinterpret_cast<f4*>(&cf[q * 1024 + swz(e)]) = v;
    }

    const int sBase = blockIdx.x * 16 + wave * 2;   // 2 samples per wave
    float x[2][16];
    #pragma unroll
    for (int m = 0; m < 2; ++m) {
        const f4* p = reinterpret_cast<const f4*>(inp + (size_t)(sBase + m) * 1024 + lane * 16);
        #pragma unroll
        for (int c = 0; c < 4; ++c) {
            f4 v = p[c];
            x[m][4*c+0] = v.x; x[m][4*c+1] = v.y; x[m][4*c+2] = v.z; x[m][4*c+3] = v.w;
        }
    }

    __syncthreads();   // cf ready

    // ---- stages 0,1 (s=1,2): pairs within each f4 quarter; coeff from LDS ----
    #pragma unroll
    for (int i = 0; i < 2; ++i) {
        const float* arow = &cf[(size_t)(2*i)     * 1024];
        const float* brow = &cf[(size_t)(2*i + 1) * 1024];
        #pragma unroll
        for (int c = 0; c < 4; ++c) {
            f4 va = *reinterpret_cast<const f4*>(&arow[swz(lane * 16 + 4 * c)]);
            f4 vb = *reinterpret_cast<const f4*>(&brow[swz(lane * 16 + 4 * c)]);
            #pragma unroll
            for (int m = 0; m < 2; ++m) {
                float* xm = x[m];
                if (i == 0) {          // pairs (0,1),(2,3)
                    float lo0 = xm[4*c+0], hi0 = xm[4*c+1];
                    xm[4*c+0] = va[0] * lo0 + vb[1] * hi0;
                    xm[4*c+1] = va[1] * hi0 + vb[0] * lo0;
                    float lo1 = xm[4*c+2], hi1 = xm[4*c+3];
                    xm[4*c+2] = va[2] * lo1 + vb[3] * hi1;
                    xm[4*c+3] = va[3] * hi1 + vb[2] * lo1;
                } else {               // pairs (0,2),(1,3)
                    float lo0 = xm[4*c+0], hi0 = xm[4*c+2];
                    xm[4*c+0] = va[0] * lo0 + vb[2] * hi0;
                    xm[4*c+2] = va[2] * hi0 + vb[0] * lo0;
                    float lo1 = xm[4*c+1], hi1 = xm[4*c+3];
                    xm[4*c+1] = va[1] * lo1 + vb[3] * hi1;
                    xm[4*c+3] = va[3] * hi1 + vb[1] * lo1;
                }
            }
        }
    }

    // ---- stages 2,3 (s=4,8): pairs across quarters; coeff from LDS ----
    #pragma unroll
    for (int i = 2; i < 4; ++i) {
        const float* arow = &cf[(size_t)(2*i)     * 1024];
        const float* brow = &cf[(size_t)(2*i + 1) * 1024];
        #pragma unroll
        for (int g = 0; g < 2; ++g) {
            const int q0 = (i == 2) ? 2 * g : g;       // s=4: (0,1),(2,3)
            const int q1 = (i == 2) ? q0 + 1 : q0 + 2; // s=8: (0,2),(1,3)
            f4 va0 = *reinterpret_cast<const f4*>(&arow[swz(lane * 16 + 4 * q0)]);
            f4 va1 = *reinterpret_cast<const f4*>(&arow[swz(lane * 16 + 4 * q1)]);
            f4 vb0 = *reinterpret_cast<const f4*>(&brow[swz(lane * 16 + 4 * q0)]);
            f4 vb1 = *reinterpret_cast<const f4*>(&brow[swz(lane * 16 + 4 * q1)]);
            #pragma unroll
            for (int m = 0; m < 2; ++m) {
                float* xm = x[m];
                #pragma unroll
                for (int e = 0; e < 4; ++e) {
                    float lo = xm[4*q0+e], hi = xm[4*q1+e];
                    xm[4*q0+e] = va0[e] * lo + vb1[e] * hi;
                    xm[4*q1+e] = va1[e] * hi + vb0[e] * lo;
                }
            }
        }
    }

    // ---- stage 4 (d=1): DPP quad_perm exchange; coeff rows 8,9 from LDS ----
    {
        const float* arow = &cf[(size_t)8 * 1024];
        const float* brow = &cf[(size_t)9 * 1024];
        #pragma unroll
        for (int c = 0; c < 4; ++c) {
            f4 va = *reinterpret_cast<const f4*>(&arow[swz(lane * 16 + 4 * c)]);
            f4 vb = *reinterpret_cast<const f4*>(&brow[swz((lane ^ 1) * 16 + 4 * c)]);
            #pragma unroll
            for (int m = 0; m < 2; ++m) {
                #pragma unroll
                for (int e = 0; e < 4; ++e) {
                    float v = x[m][4*c+e];
                    x[m][4*c+e] = va[e] * v + vb[e] * dppx<0xB1>(v);
                }
            }
        }
    }

    // ---- stages 5..9 (d=2,4,8,16,32): coeff rows 10..19 from LDS ----
    // exchange pipes: d=2,8 DPP | d=4 shfl (DS) | d=16,32 permlane builtin
    #pragma unroll
    for (int i = 5; i < 10; ++i) {
        const int d = 1 << (i - 4);
        const float* arow = &cf[(size_t)(2*i)     * 1024];
        const float* brow = &cf[(size_t)(2*i + 1) * 1024];
        #pragma unroll
        for (int c = 0; c < 4; ++c) {
            f4 va = *reinterpret_cast<const f4*>(&arow[swz(lane * 16 + 4 * c)]);
            f4 vb = *reinterpret_cast<const f4*>(&brow[swz((lane ^ d) * 16 + 4 * c)]);
            #pragma unroll
            for (int m = 0; m < 2; ++m) {
                #pragma unroll
                for (int e = 0; e < 4; ++e) {
                    float v = x[m][4*c+e];
                    float xp = (d == 2)  ? dppx<0x4E>(v)
                             : (d == 8)  ? dppx<0x128>(v)
                             : (d == 16) ? xswap16(v)
                             : (d == 32) ? xswap32(v)
                             :             __shfl_xor(v, d, 64);   // d = 4
                    x[m][4*c+e] = va[e] * v + vb[e] * xp;
                }
            }
        }
    }

    __syncthreads();   // all coeff reads done; overlay z onto cf rows 0..15

    // z write (R7-verified slot algebra) into this wave's overlay region.
    float* zz = &cf[(size_t)wave * 2048];              // 1024 f2 slots
    const int km0 = (lane & 7) << 1;                   // pair-preserving swizzle
    #pragma unroll
    for (int k = 0; k < 16; k += 2) {
        int pi = lane * 16 + (k ^ km0);
        f4 v = { x[0][k], x[1][k], x[0][k+1], x[1][k+1] };
        *reinterpret_cast<f4*>(&zz[2 * pi]) = v;
    }

    // epilogue (R7-verified): one b64 LDS read serves both samples; srv/scv
    // pipelined 1 deep ahead of the stores. Wave-private region, no barrier.
    const i4* srv = reinterpret_cast<const i4*>(src2);
    const f4* scv = reinterpret_cast<const f4*>(scale);
    f4* o0 = reinterpret_cast<f4*>(out + (size_t)sBase * 4096);
    f4* o1 = reinterpret_cast<f4*>(out + (size_t)(sBase + 1) * 4096);

    i4 si = srv[lane];
    f4 sc = scv[lane];
    #pragma unroll
    for (int it = 0; it < 16; ++it) {
        i4 si_c = si;
        f4 sc_c = sc;
        if (it + 1 < 16) {                      // prefetch next iteration
            si = srv[(it + 1) * 64 + lane];
            sc = scv[(it + 1) * 64 + lane];
        }
        int j4 = it * 64 + lane;
        f2 vx = *reinterpret_cast<const f2*>(&zz[2 * si_c.x]);
        f2 vy = *reinterpret_cast<const f2*>(&zz[2 * si_c.y]);
        f2 vz = *reinterpret_cast<const f2*>(&zz[2 * si_c.z]);
        f2 vw = *reinterpret_cast<const f2*>(&zz[2 * si_c.w]);
        f4 r0 = { sc_c.x * vx.x, sc_c.y * vy.x, sc_c.z * vz.x, sc_c.w * vw.x };
        f4 r1 = { sc_c.x * vx.y, sc_c.y * vy.y, sc_c.z * vz.y, sc_c.w * vw.y };
        o0[j4] = r0;
        o1[j4] = r1;
    }
}

extern "C" void kernel_launch(void* const* d_in, const int* in_sizes, int n_in,
                              void* d_out, int out_size, void* d_ws, size_t ws_size,
                              hipStream_t stream) {
    const float* inp  = (const float*)d_in[0];   // (8192, 1024) f32
    const float* lp   = (const float*)d_in[1];   // (24, 4096)  f32
    const int*   orow = (const int*)d_in[2];     // (4096,)     i32
    float* out = (float*)d_out;                  // (8192, 4096) f32

    float* scale = (float*)d_ws;                       // 4096 f32
    int*   src2  = (int*)((char*)d_ws + 4096 * 4);     // 4096 i32 (f2-slot idx)

    bfly_prep<<<16, 256, 0, stream>>>(lp, orow, scale, src2);
    bfly_main<<<512, 512, 0, stream>>>(inp, lp, scale, src2, out);
}

// Round 22
// 43.265 us; speedup vs baseline: 1.0669x; 1.0114x over previous
//
#include <hip/hip_runtime.h>

// OurButterflyLayer: N=4096, LOGN=12, IN=1024, OUT=4096, BATCH=8192
//
// out[s,j] = scale[j] * z_s[src[j]],  z_s = 10-stage butterfly (stages 0..9)
// on the 1024-float input row s; stages 10,11 + out-row gather fold into
// per-output (scale, src) pairs (elements >=1024 stay zero through stages
// 0..9 since all strides < 1024).
//
// Round-22: the untested matrix cell — 4 samples/wave at 8 waves/CU without
// spills. R11/R14 spilled here because a[16]/b[16] arrays pushed live set
// ~130 > the hard 128-VGPR cap of 512-thr blocks; quarter-consumed coeffs
// (R10-verified) keep peak live ~100. Structure: grid 256 x 512 thr
// (1 block/CU, single generation, coeffs staged once), all 20 coeff rows in
// 80 KB swizzled LDS (R13), separate 8 KB/wave paired-f2 z scratch (144 KB
// total), exchanges = R19-verified (DPP d=1,2,8 | shfl d=4 | permlane
// builtin d=16,32), TWO-PASS epilogue: zwrite+emit for samples (0,1) then
// (2,3) — per-sample coeff DS reads halve vs R19. One barrier, plain
// loads/stores, pipelined epilogue. p-loop unrolled so all x[] indices are
// compile-time static (no scratch from dynamic indexing).

typedef float f4 __attribute__((ext_vector_type(4)));
typedef float f2 __attribute__((ext_vector_type(2)));
typedef int   i4 __attribute__((ext_vector_type(4)));

__device__ __forceinline__ int swz(int e) {
    // XOR float-index bits [6:5] into [3:2]: keeps float4 alignment; makes
    // 64B-stride LDS coeff accesses bank-conflict-free.
    return e ^ (((e >> 5) & 3) << 2);
}

template<int CTRL>
__device__ __forceinline__ float dppx(float x) {
    int xi = __builtin_bit_cast(int, x);
    int r  = __builtin_amdgcn_update_dpp(xi, xi, CTRL, 0xF, 0xF, true);
    return __builtin_bit_cast(float, r);
}
// ctrl: quad_perm(1,0,3,2)=0xB1 (lane^1), quad_perm(2,3,0,1)=0x4E (lane^2),
// row_ror:8=0x128 (lane^8 within 16-lane row). Verified R4/R6/R7/R10/R13/R19.

#if __has_builtin(__builtin_amdgcn_permlane16_swap) && __has_builtin(__builtin_amdgcn_permlane32_swap)
// lane^16 / lane^32 partner via permlane swap builtin (compiler handles the
// DPP-class read-after-write hazards). XOR-combine is exact and
// direction-proof. Verified R19.
__device__ __forceinline__ float xswap16(float x) {
    unsigned xi = __builtin_bit_cast(unsigned, x);
    auto r = __builtin_amdgcn_permlane16_swap(xi, xi, false, false);
    return __builtin_bit_cast(float, r[0] ^ r[1] ^ xi);
}
__device__ __forceinline__ float xswap32(float x) {
    unsigned xi = __builtin_bit_cast(unsigned, x);
    auto r = __builtin_amdgcn_permlane32_swap(xi, xi, false, false);
    return __builtin_bit_cast(float, r[0] ^ r[1] ^ xi);
}
#else
__device__ __forceinline__ float xswap16(float x) { return __shfl_xor(x, 16, 64); }
__device__ __forceinline__ float xswap32(float x) { return __shfl_xor(x, 32, 64); }
#endif

__global__ void __launch_bounds__(256) bfly_prep(
    const float* __restrict__ lp, const int* __restrict__ orow,
    float* __restrict__ scale, int* __restrict__ src2)
{
    int j = blockIdx.x * 256 + threadIdx.x;
    if (j >= 4096) return;
    int r = orow[j];
    int c = r & 1023;
    int u = r & 2047;
    const float* A10 = lp + 20 * 4096;
    const float* B10 = lp + 21 * 4096;
    const float* A11 = lp + 22 * 4096;
    const float* B11 = lp + 23 * 4096;
    float f11 = (r & 2048) ? B11[u] : A11[u];
    float f10 = (r & 1024) ? B10[c] : A10[c];
    scale[j] = f11 * f10;
    // f2-slot index with pair-preserving bank spread:
    // pz(c) = c ^ (((c>>4)&7)<<1)   (matches z-write slot algebra below)
    src2[j] = c ^ (((c >> 4) & 7) << 1);
}

__global__ void __launch_bounds__(512, 2) bfly_main(
    const float* __restrict__ inp, const float* __restrict__ lp,
    const float* __restrict__ scale, const int* __restrict__ src2,
    float* __restrict__ out)
{
    // [0, 20480): 20 coeff rows (stages 0..9 a,b), swizzled. persistent.
    // [20480, 36864): 8 waves x 1024 paired-f2 z slots (8 KB each).
    __shared__ __align__(16) float cf[20 * 1024 + 8 * 2048];
    const int t = threadIdx.x;
    const int wave = t >> 6, lane = t & 63;

    // cooperative coeff staging: rows 0..19 of lp (first 1024 floats each);
    // 512 threads stage two rows per step. ONCE per CU (grid 256).
    #pragma unroll
    for (int step = 0; step < 10; ++step) {
        const int q = 2 * step + (t >> 8);
        const int e = (t & 255) * 4;
        const f4 v = *reinterpret_cast<const f4*>(lp + (size_t)q * 4096 + e);
        *reinterpret_cast<f4*>(&cf[q * 1024 + swz(e)]) = v;
    }

    const int sBase = blockIdx.x * 32 + wave * 4;   // 4 samples per wave
    float x[4][16];
    #pragma unroll
    for (int m = 0; m < 4; ++m) {
        const f4* p = reinterpret_cast<const f4*>(inp + (size_t)(sBase + m) * 1024 + lane * 16);
        #pragma unroll
        for (int c = 0; c < 4; ++c) {
            f4 v = p[c];
            x[m][4*c+0] = v.x; x[m][4*c+1] = v.y; x[m][4*c+2] = v.z; x[m][4*c+3] = v.w;
        }
    }

    __syncthreads();   // cf ready — the only barrier in the kernel

    // ---- stages 0,1 (s=1,2): pairs within each f4 quarter; coeff from LDS ----
    // quarter-consumed (R10): only va,vb (8 regs) live per step, never a[16]/b[16]
    #pragma unroll
    for (int i = 0; i < 2; ++i) {
        const float* arow = &cf[(size_t)(2*i)     * 1024];
        const float* brow = &cf[(size_t)(2*i + 1) * 1024];
        #pragma unroll
        for (int c = 0; c < 4; ++c) {
            f4 va = *reinterpret_cast<const f4*>(&arow[swz(lane * 16 + 4 * c)]);
            f4 vb = *reinterpret_cast<const f4*>(&brow[swz(lane * 16 + 4 * c)]);
            #pragma unroll
            for (int m = 0; m < 4; ++m) {
                float* xm = x[m];
                if (i == 0) {          // pairs (0,1),(2,3)
                    float lo0 = xm[4*c+0], hi0 = xm[4*c+1];
                    xm[4*c+0] = va[0] * lo0 + vb[1] * hi0;
                    xm[4*c+1] = va[1] * hi0 + vb[0] * lo0;
                    float lo1 = xm[4*c+2], hi1 = xm[4*c+3];
                    xm[4*c+2] = va[2] * lo1 + vb[3] * hi1;
                    xm[4*c+3] = va[3] * hi1 + vb[2] * lo1;
                } else {               // pairs (0,2),(1,3)
                    float lo0 = xm[4*c+0], hi0 = xm[4*c+2];
                    xm[4*c+0] = va[0] * lo0 + vb[2] * hi0;
                    xm[4*c+2] = va[2] * hi0 + vb[0] * lo0;
                    float lo1 = xm[4*c+1], hi1 = xm[4*c+3];
                    xm[4*c+1] = va[1] * lo1 + vb[3] * hi1;
                    xm[4*c+3] = va[3] * hi1 + vb[1] * lo1;
                }
            }
        }
    }

    // ---- stages 2,3 (s=4,8): pairs across quarters; coeff from LDS ----
    #pragma unroll
    for (int i = 2; i < 4; ++i) {
        const float* arow = &cf[(size_t)(2*i)     * 1024];
        const float* brow = &cf[(size_t)(2*i + 1) * 1024];
        #pragma unroll
        for (int g = 0; g < 2; ++g) {
            const int q0 = (i == 2) ? 2 * g : g;       // s=4: (0,1),(2,3)
            const int q1 = (i == 2) ? q0 + 1 : q0 + 2; // s=8: (0,2),(1,3)
            f4 va0 = *reinterpret_cast<const f4*>(&arow[swz(lane * 16 + 4 * q0)]);
            f4 va1 = *reinterpret_cast<const f4*>(&arow[swz(lane * 16 + 4 * q1)]);
            f4 vb0 = *reinterpret_cast<const f4*>(&brow[swz(lane * 16 + 4 * q0)]);
            f4 vb1 = *reinterpret_cast<const f4*>(&brow[swz(lane * 16 + 4 * q1)]);
            #pragma unroll
            for (int m = 0; m < 4; ++m) {
                float* xm = x[m];
                #pragma unroll
                for (int e = 0; e < 4; ++e) {
                    float lo = xm[4*q0+e], hi = xm[4*q1+e];
                    xm[4*q0+e] = va0[e] * lo + vb1[e] * hi;
                    xm[4*q1+e] = va1[e] * hi + vb0[e] * lo;
                }
            }
        }
    }

    // ---- stage 4 (d=1): DPP quad_perm exchange; coeff rows 8,9 from LDS ----
    {
        const float* arow = &cf[(size_t)8 * 1024];
        const float* brow = &cf[(size_t)9 * 1024];
        #pragma unroll
        for (int c = 0; c < 4; ++c) {
            f4 va = *reinterpret_cast<const f4*>(&arow[swz(lane * 16 + 4 * c)]);
            f4 vb = *reinterpret_cast<const f4*>(&brow[swz((lane ^ 1) * 16 + 4 * c)]);
            #pragma unroll
            for (int m = 0; m < 4; ++m) {
                #pragma unroll
                for (int e = 0; e < 4; ++e) {
                    float v = x[m][4*c+e];
                    x[m][4*c+e] = va[e] * v + vb[e] * dppx<0xB1>(v);
                }
            }
        }
    }

    // ---- stages 5..9 (d=2,4,8,16,32): coeff rows 10..19 from LDS ----
    // exchange pipes: d=2,8 DPP | d=4 shfl (DS) | d=16,32 permlane builtin
    #pragma unroll
    for (int i = 5; i < 10; ++i) {
        const int d = 1 << (i - 4);
        const float* arow = &cf[(size_t)(2*i)     * 1024];
        const float* brow = &cf[(size_t)(2*i + 1) * 1024];
        #pragma unroll
        for (int c = 0; c < 4; ++c) {
            f4 va = *reinterpret_cast<const f4*>(&arow[swz(lane * 16 + 4 * c)]);
            f4 vb = *reinterpret_cast<const f4*>(&brow[swz((lane ^ d) * 16 + 4 * c)]);
            #pragma unroll
            for (int m = 0; m < 4; ++m) {
                #pragma unroll
                for (int e = 0; e < 4; ++e) {
                    float v = x[m][4*c+e];
                    float xp = (d == 2)  ? dppx<0x4E>(v)
                             : (d == 8)  ? dppx<0x128>(v)
                             : (d == 16) ? xswap16(v)
                             : (d == 32) ? xswap32(v)
                             :             __shfl_xor(v, d, 64);   // d = 4
                    x[m][4*c+e] = va[e] * v + vb[e] * xp;
                }
            }
        }
    }

    // two-pass epilogue: pass p handles samples (2p, 2p+1). In-wave DS
    // ordering guarantees pass-0 emit reads complete before pass-1 zwrite
    // overwrites the region. p-loop unrolled -> all x indices static.
    float* zz = &cf[20 * 1024 + (size_t)wave * 2048];  // 1024 f2 slots
    const int km0 = (lane & 7) << 1;                   // pair-preserving swizzle
    const i4* srv = reinterpret_cast<const i4*>(src2);
    const f4* scv = reinterpret_cast<const f4*>(scale);

    #pragma unroll
    for (int p = 0; p < 2; ++p) {
        // z write (R7-verified slot algebra): f2-slot pi = pz(c), c = lane*16+k
        #pragma unroll
        for (int k = 0; k < 16; k += 2) {
            int pi = lane * 16 + (k ^ km0);
            f4 v = { x[2*p+0][k], x[2*p+1][k], x[2*p+0][k+1], x[2*p+1][k+1] };
            *reinterpret_cast<f4*>(&zz[2 * pi]) = v;
        }

        // emit (R7-verified): one b64 LDS read serves both samples; srv/scv
        // pipelined 1 deep ahead of the stores. Wave-private, no barrier.
        f4* o0 = reinterpret_cast<f4*>(out + (size_t)(sBase + 2*p)     * 4096);
        f4* o1 = reinterpret_cast<f4*>(out + (size_t)(sBase + 2*p + 1) * 4096);
        i4 si = srv[lane];
        f4 sc = scv[lane];
        #pragma unroll
        for (int it = 0; it < 16; ++it) {
            i4 si_c = si;
            f4 sc_c = sc;
            if (it + 1 < 16) {                  // prefetch next iteration
                si = srv[(it + 1) * 64 + lane];
                sc = scv[(it + 1) * 64 + lane];
            }
            int j4 = it * 64 + lane;
            f2 vx = *reinterpret_cast<const f2*>(&zz[2 * si_c.x]);
            f2 vy = *reinterpret_cast<const f2*>(&zz[2 * si_c.y]);
            f2 vz = *reinterpret_cast<const f2*>(&zz[2 * si_c.z]);
            f2 vw = *reinterpret_cast<const f2*>(&zz[2 * si_c.w]);
            f4 r0 = { sc_c.x * vx.x, sc_c.y * vy.x, sc_c.z * vz.x, sc_c.w * vw.x };
            f4 r1 = { sc_c.x * vx.y, sc_c.y * vy.y, sc_c.z * vz.y, sc_c.w * vw.y };
            o0[j4] = r0;
            o1[j4] = r1;
        }
    }
}

extern "C" void kernel_launch(void* const* d_in, const int* in_sizes, int n_in,
                              void* d_out, int out_size, void* d_ws, size_t ws_size,
                              hipStream_t stream) {
    const float* inp  = (const float*)d_in[0];   // (8192, 1024) f32
    const float* lp   = (const float*)d_in[1];   // (24, 4096)  f32
    const int*   orow = (const int*)d_in[2];     // (4096,)     i32
    float* out = (float*)d_out;                  // (8192, 4096) f32

    float* scale = (float*)d_ws;                       // 4096 f32
    int*   src2  = (int*)((char*)d_ws + 4096 * 4);     // 4096 i32 (f2-slot idx)

    bfly_prep<<<16, 256, 0, stream>>>(lp, orow, scale, src2);
    bfly_main<<<256, 512, 0, stream>>>(inp, lp, scale, src2, out);
}

// Round 23
// 41.520 us; speedup vs baseline: 1.1117x; 1.0420x over previous
//
#include <hip/hip_runtime.h>

// OurButterflyLayer: N=4096, LOGN=12, IN=1024, OUT=4096, BATCH=8192
//
// out[s,j] = scale[j] * z_s[src[j]],  z_s = 10-stage butterfly (stages 0..9)
// on the 1024-float input row s; stages 10,11 + out-row gather fold into
// per-output (scale, src) pairs (elements >=1024 stay zero through stages
// 0..9 since all strides < 1024).
//
// Round-23: R19 (best, 41.8 us) with the LAST DS-pipe shuffle (d=4) moved to
// VALU: dual-DPP row_shl:4 / row_shr:4 computed unconditionally (full EXEC)
// + v_cndmask select on lane&4. Both values are named SSA values before the
// ternary -> LLVM lowers to select, no divergent branch possible; bound_ctrl
// zeros land only in discarded lanes. (R5's version was swapped shl/shr AND
// bundled with the broken asm permlane.) After this, ZERO ds_bpermutes
// remain: d=1,2,8 DPP | d=4 dual-DPP+cndmask | d=16,32 permlane builtin.
// Everything else R19 byte-identical: 512 blocks x 512 thr, all 20 coeff
// rows in 80 KB swizzled LDS, 8 KB/wave paired-f2 z scratch, one barrier,
// plain loads/stores, pipelined f2-paired epilogue.

typedef float f4 __attribute__((ext_vector_type(4)));
typedef float f2 __attribute__((ext_vector_type(2)));
typedef int   i4 __attribute__((ext_vector_type(4)));

__device__ __forceinline__ int swz(int e) {
    // XOR float-index bits [6:5] into [3:2]: keeps float4 alignment; makes
    // 64B-stride LDS coeff accesses bank-conflict-free.
    return e ^ (((e >> 5) & 3) << 2);
}

template<int CTRL>
__device__ __forceinline__ float dppx(float x) {
    int xi = __builtin_bit_cast(int, x);
    int r  = __builtin_amdgcn_update_dpp(xi, xi, CTRL, 0xF, 0xF, true);
    return __builtin_bit_cast(float, r);
}
// ctrl: quad_perm(1,0,3,2)=0xB1 (lane^1), quad_perm(2,3,0,1)=0x4E (lane^2),
// row_shl:4=0x104 (dest[i]=src[i+4]), row_shr:4=0x114 (dest[i]=src[i-4]),
// row_ror:8=0x128 (lane^8 within 16-lane row). 0xB1/0x4E/0x128 verified
// R4/R6/R7/R10/R13/R19.

#if __has_builtin(__builtin_amdgcn_permlane16_swap) && __has_builtin(__builtin_amdgcn_permlane32_swap)
// lane^16 / lane^32 partner via permlane swap builtin (compiler handles the
// DPP-class read-after-write hazards). XOR-combine is exact and
// direction-proof. Verified R19.
__device__ __forceinline__ float xswap16(float x) {
    unsigned xi = __builtin_bit_cast(unsigned, x);
    auto r = __builtin_amdgcn_permlane16_swap(xi, xi, false, false);
    return __builtin_bit_cast(float, r[0] ^ r[1] ^ xi);
}
__device__ __forceinline__ float xswap32(float x) {
    unsigned xi = __builtin_bit_cast(unsigned, x);
    auto r = __builtin_amdgcn_permlane32_swap(xi, xi, false, false);
    return __builtin_bit_cast(float, r[0] ^ r[1] ^ xi);
}
#else
__device__ __forceinline__ float xswap16(float x) { return __shfl_xor(x, 16, 64); }
__device__ __forceinline__ float xswap32(float x) { return __shfl_xor(x, 32, 64); }
#endif

// d=4 exchange on VALU: both row-shift DPPs computed under full EXEC, then
// per-lane select. Lanes with (lane&4)==0 need partner lane+4 -> row_shl:4;
// lanes with (lane&4)!=0 need lane-4 -> row_shr:4. Out-of-row reads (sl for
// row-lanes 12..15, sr for 0..3) produce bound_ctrl values only in lanes the
// select discards.
__device__ __forceinline__ float xchg4(float v, int lane) {
    float sl = dppx<0x104>(v);   // dest[i] = src[i+4]
    float sr = dppx<0x114>(v);   // dest[i] = src[i-4]
    return (lane & 4) ? sr : sl;
}

__global__ void __launch_bounds__(256) bfly_prep(
    const float* __restrict__ lp, const int* __restrict__ orow,
    float* __restrict__ scale, int* __restrict__ src2)
{
    int j = blockIdx.x * 256 + threadIdx.x;
    if (j >= 4096) return;
    int r = orow[j];
    int c = r & 1023;
    int u = r & 2047;
    const float* A10 = lp + 20 * 4096;
    const float* B10 = lp + 21 * 4096;
    const float* A11 = lp + 22 * 4096;
    const float* B11 = lp + 23 * 4096;
    float f11 = (r & 2048) ? B11[u] : A11[u];
    float f10 = (r & 1024) ? B10[c] : A10[c];
    scale[j] = f11 * f10;
    // f2-slot index with pair-preserving bank spread:
    // pz(c) = c ^ (((c>>4)&7)<<1)   (matches z-write slot algebra below)
    src2[j] = c ^ (((c >> 4) & 7) << 1);
}

__global__ void __launch_bounds__(512, 2) bfly_main(
    const float* __restrict__ inp, const float* __restrict__ lp,
    const float* __restrict__ scale, const int* __restrict__ src2,
    float* __restrict__ out)
{
    // [0, 20480): 20 coeff rows (stages 0..9 a,b), swizzled. persistent.
    // [20480, 36864): 8 waves x 1024 paired-f2 z slots (8 KB each).
    __shared__ __align__(16) float cf[20 * 1024 + 8 * 2048];
    const int t = threadIdx.x;
    const int wave = t >> 6, lane = t & 63;

    // cooperative coeff staging: rows 0..19 of lp (first 1024 floats each);
    // 512 threads stage two rows per step.
    #pragma unroll
    for (int step = 0; step < 10; ++step) {
        const int q = 2 * step + (t >> 8);
        const int e = (t & 255) * 4;
        const f4 v = *reinterpret_cast<const f4*>(lp + (size_t)q * 4096 + e);
        *reinterpret_cast<f4*>(&cf[q * 1024 + swz(e)]) = v;
    }

    const int sBase = blockIdx.x * 16 + wave * 2;   // 2 samples per wave
    float x[2][16];
    #pragma unroll
    for (int m = 0; m < 2; ++m) {
        const f4* p = reinterpret_cast<const f4*>(inp + (size_t)(sBase + m) * 1024 + lane * 16);
        #pragma unroll
        for (int c = 0; c < 4; ++c) {
            f4 v = p[c];
            x[m][4*c+0] = v.x; x[m][4*c+1] = v.y; x[m][4*c+2] = v.z; x[m][4*c+3] = v.w;
        }
    }

    __syncthreads();   // cf ready — the only barrier in the kernel

    // ---- stages 0,1 (s=1,2): pairs within each f4 quarter; coeff from LDS ----
    #pragma unroll
    for (int i = 0; i < 2; ++i) {
        const float* arow = &cf[(size_t)(2*i)     * 1024];
        const float* brow = &cf[(size_t)(2*i + 1) * 1024];
        #pragma unroll
        for (int c = 0; c < 4; ++c) {
            f4 va = *reinterpret_cast<const f4*>(&arow[swz(lane * 16 + 4 * c)]);
            f4 vb = *reinterpret_cast<const f4*>(&brow[swz(lane * 16 + 4 * c)]);
            #pragma unroll
            for (int m = 0; m < 2; ++m) {
                float* xm = x[m];
                if (i == 0) {          // pairs (0,1),(2,3)
                    float lo0 = xm[4*c+0], hi0 = xm[4*c+1];
                    xm[4*c+0] = va[0] * lo0 + vb[1] * hi0;
                    xm[4*c+1] = va[1] * hi0 + vb[0] * lo0;
                    float lo1 = xm[4*c+2], hi1 = xm[4*c+3];
                    xm[4*c+2] = va[2] * lo1 + vb[3] * hi1;
                    xm[4*c+3] = va[3] * hi1 + vb[2] * lo1;
                } else {               // pairs (0,2),(1,3)
                    float lo0 = xm[4*c+0], hi0 = xm[4*c+2];
                    xm[4*c+0] = va[0] * lo0 + vb[2] * hi0;
                    xm[4*c+2] = va[2] * hi0 + vb[0] * lo0;
                    float lo1 = xm[4*c+1], hi1 = xm[4*c+3];
                    xm[4*c+1] = va[1] * lo1 + vb[3] * hi1;
                    xm[4*c+3] = va[3] * hi1 + vb[1] * lo1;
                }
            }
        }
    }

    // ---- stages 2,3 (s=4,8): pairs across quarters; coeff from LDS ----
    #pragma unroll
    for (int i = 2; i < 4; ++i) {
        const float* arow = &cf[(size_t)(2*i)     * 1024];
        const float* brow = &cf[(size_t)(2*i + 1) * 1024];
        #pragma unroll
        for (int g = 0; g < 2; ++g) {
            const int q0 = (i == 2) ? 2 * g : g;       // s=4: (0,1),(2,3)
            const int q1 = (i == 2) ? q0 + 1 : q0 + 2; // s=8: (0,2),(1,3)
            f4 va0 = *reinterpret_cast<const f4*>(&arow[swz(lane * 16 + 4 * q0)]);
            f4 va1 = *reinterpret_cast<const f4*>(&arow[swz(lane * 16 + 4 * q1)]);
            f4 vb0 = *reinterpret_cast<const f4*>(&brow[swz(lane * 16 + 4 * q0)]);
            f4 vb1 = *reinterpret_cast<const f4*>(&brow[swz(lane * 16 + 4 * q1)]);
            #pragma unroll
            for (int m = 0; m < 2; ++m) {
                float* xm = x[m];
                #pragma unroll
                for (int e = 0; e < 4; ++e) {
                    float lo = xm[4*q0+e], hi = xm[4*q1+e];
                    xm[4*q0+e] = va0[e] * lo + vb1[e] * hi;
                    xm[4*q1+e] = va1[e] * hi + vb0[e] * lo;
                }
            }
        }
    }

    // ---- stage 4 (d=1): DPP quad_perm exchange; coeff rows 8,9 from LDS ----
    {
        const float* arow = &cf[(size_t)8 * 1024];
        const float* brow = &cf[(size_t)9 * 1024];
        #pragma unroll
        for (int c = 0; c < 4; ++c) {
            f4 va = *reinterpret_cast<const f4*>(&arow[swz(lane * 16 + 4 * c)]);
            f4 vb = *reinterpret_cast<const f4*>(&brow[swz((lane ^ 1) * 16 + 4 * c)]);
            #pragma unroll
            for (int m = 0; m < 2; ++m) {
                #pragma unroll
                for (int e = 0; e < 4; ++e) {
                    float v = x[m][4*c+e];
                    x[m][4*c+e] = va[e] * v + vb[e] * dppx<0xB1>(v);
                }
            }
        }
    }

    // ---- stages 5..9 (d=2,4,8,16,32): coeff rows 10..19 from LDS ----
    // ALL exchanges on VALU: d=2,8 DPP | d=4 dual-DPP+cndmask | d=16,32
    // permlane builtin. Zero DS shuffles remain.
    #pragma unroll
    for (int i = 5; i < 10; ++i) {
        const int d = 1 << (i - 4);
        const float* arow = &cf[(size_t)(2*i)     * 1024];
        const float* brow = &cf[(size_t)(2*i + 1) * 1024];
        #pragma unroll
        for (int c = 0; c < 4; ++c) {
            f4 va = *reinterpret_cast<const f4*>(&arow[swz(lane * 16 + 4 * c)]);
            f4 vb = *reinterpret_cast<const f4*>(&brow[swz((lane ^ d) * 16 + 4 * c)]);
            #pragma unroll
            for (int m = 0; m < 2; ++m) {
                #pragma unroll
                for (int e = 0; e < 4; ++e) {
                    float v = x[m][4*c+e];
                    float xp = (d == 2)  ? dppx<0x4E>(v)
                             : (d == 4)  ? xchg4(v, lane)
                             : (d == 8)  ? dppx<0x128>(v)
                             : (d == 16) ? xswap16(v)
                             :             xswap32(v);
                    x[m][4*c+e] = va[e] * v + vb[e] * xp;
                }
            }
        }
    }

    // z write (R7-verified slot algebra) into this wave's private region.
    float* zz = &cf[20 * 1024 + (size_t)wave * 2048];  // 1024 f2 slots
    const int km0 = (lane & 7) << 1;                   // pair-preserving swizzle
    #pragma unroll
    for (int k = 0; k < 16; k += 2) {
        int pi = lane * 16 + (k ^ km0);
        f4 v = { x[0][k], x[1][k], x[0][k+1], x[1][k+1] };
        *reinterpret_cast<f4*>(&zz[2 * pi]) = v;
    }

    // epilogue (R7-verified): one b64 LDS read serves both samples; srv/scv
    // pipelined 1 deep ahead of the stores. Wave-private region, no barrier.
    const i4* srv = reinterpret_cast<const i4*>(src2);
    const f4* scv = reinterpret_cast<const f4*>(scale);
    f4* o0 = reinterpret_cast<f4*>(out + (size_t)sBase * 4096);
    f4* o1 = reinterpret_cast<f4*>(out + (size_t)(sBase + 1) * 4096);

    i4 si = srv[lane];
    f4 sc = scv[lane];
    #pragma unroll
    for (int it = 0; it < 16; ++it) {
        i4 si_c = si;
        f4 sc_c = sc;
        if (it + 1 < 16) {                      // prefetch next iteration
            si = srv[(it + 1) * 64 + lane];
            sc = scv[(it + 1) * 64 + lane];
        }
        int j4 = it * 64 + lane;
        f2 vx = *reinterpret_cast<const f2*>(&zz[2 * si_c.x]);
        f2 vy = *reinterpret_cast<const f2*>(&zz[2 * si_c.y]);
        f2 vz = *reinterpret_cast<const f2*>(&zz[2 * si_c.z]);
        f2 vw = *reinterpret_cast<const f2*>(&zz[2 * si_c.w]);
        f4 r0 = { sc_c.x * vx.x, sc_c.y * vy.x, sc_c.z * vz.x, sc_c.w * vw.x };
        f4 r1 = { sc_c.x * vx.y, sc_c.y * vy.y, sc_c.z * vz.y, sc_c.w * vw.y };
        o0[j4] = r0;
        o1[j4] = r1;
    }
}

extern "C" void kernel_launch(void* const* d_in, const int* in_sizes, int n_in,
                              void* d_out, int out_size, void* d_ws, size_t ws_size,
                              hipStream_t stream) {
    const float* inp  = (const float*)d_in[0];   // (8192, 1024) f32
    const float* lp   = (const float*)d_in[1];   // (24, 4096)  f32
    const int*   orow = (const int*)d_in[2];     // (4096,)     i32
    float* out = (float*)d_out;                  // (8192, 4096) f32

    float* scale = (float*)d_ws;                       // 4096 f32
    int*   src2  = (int*)((char*)d_ws + 4096 * 4);     // 4096 i32 (f2-slot idx)

    bfly_prep<<<16, 256, 0, stream>>>(lp, orow, scale, src2);
    bfly_main<<<512, 512, 0, stream>>>(inp, lp, scale, src2, out);
}